// Round 3
// baseline (96.520 us; speedup 1.0000x reference)
//
#include <hip/hip_runtime.h>
#include <math.h>

#define BB 16
#define NN 2048
#define MM 16
#define SS 128

__constant__ const float kFourPi = 12.566370614359172f;

// ---------------------------------------------------------------------------
// Kernel A: one block per (b,m), 1024 threads (16 waves).
//  - loads pcl[b,:,m,:] (AoS, 2048x3) into LDS SoA
//  - loads prim[b,m,:,:] (128x3) into LDS
//  - 4 s-subgroups x 256 threads; each thread: 8 n in regs, 32 s from LDS
//  - in-block combine: d1[bm][n] (2 MB total), d2sum[bm]
//  - block 0 zeroes the completion counter for kernel B
// ---------------------------------------------------------------------------
__global__ __launch_bounds__(1024) void fused_dist_kernel(
    const float* __restrict__ pcl,    // (B,N,M,3)
    const float* __restrict__ prim,   // (B,M,S,3)
    float* __restrict__ d1,           // [256][2048]
    float* __restrict__ d2sum,        // [256]
    unsigned int* __restrict__ counter)
{
    const int bm  = blockIdx.x;
    const int b   = bm >> 4;
    const int m   = bm & 15;
    const int tid = threadIdx.x;

    __shared__ float Qx[NN], Qy[NN], Qz[NN];   // 24 KB
    __shared__ float Px[SS], Py[SS], Pz[SS];   // 1.5 KB
    __shared__ float d1s[4][NN];               // 32 KB
    __shared__ float wmin[16][32];             // 2 KB
    __shared__ float red[2];

    if (bm == 0 && tid == 0)
        __hip_atomic_store(counter, 0u, __ATOMIC_RELAXED, __HIP_MEMORY_SCOPE_AGENT);

    // stage pcl (uncoalesced 12B/192B pattern, but L3-resident; 2 points/thread)
    {
        const size_t base = ((size_t)(b * NN) * MM + m) * 3;
#pragma unroll
        for (int j = 0; j < 2; ++j) {
            const int n = tid + j * 1024;
            const float* q = pcl + base + (size_t)n * (MM * 3);
            Qx[n] = q[0]; Qy[n] = q[1]; Qz[n] = q[2];
        }
    }
    if (tid < SS) {
        const float* pp = prim + ((size_t)bm * SS + tid) * 3;
        Px[tid] = pp[0]; Py[tid] = pp[1]; Pz[tid] = pp[2];
    }
    __syncthreads();

    const int sub  = tid >> 8;   // s-chunk 0..3
    const int stid = tid & 255;
    const int s0   = sub * 32;
    const int wid  = tid >> 6;   // 0..15
    const int lane = tid & 63;

    float qx[8], qy[8], qz[8], d1min[8];
#pragma unroll
    for (int j = 0; j < 8; ++j) {
        const int n = stid + j * 256;
        qx[j] = Qx[n]; qy[j] = Qy[n]; qz[j] = Qz[n];
        d1min[j] = 3.0e38f;
    }

#pragma unroll 4
    for (int s = 0; s < 32; ++s) {
        const float px = Px[s0 + s], py = Py[s0 + s], pz = Pz[s0 + s];
        float lmin = 3.0e38f;
#pragma unroll
        for (int j = 0; j < 8; ++j) {
            const float dx = px - qx[j];
            const float dy = py - qy[j];
            const float dz = pz - qz[j];
            float d = dx * dx;
            d = fmaf(dy, dy, d);
            d = fmaf(dz, dz, d);
            d1min[j] = fminf(d1min[j], d);
            lmin     = fminf(lmin, d);
        }
#pragma unroll
        for (int off = 32; off > 0; off >>= 1)
            lmin = fminf(lmin, __shfl_down(lmin, off, 64));
        if (lane == 0) wmin[wid][s] = lmin;
    }

#pragma unroll
    for (int j = 0; j < 8; ++j)
        d1s[sub][stid + j * 256] = d1min[j];
    __syncthreads();

    // final d1: min over the 4 s-chunks, coalesced global write
#pragma unroll
    for (int j = 0; j < 2; ++j) {
        const int n = tid + j * 1024;
        d1[(size_t)bm * NN + n] = fminf(fminf(d1s[0][n], d1s[1][n]),
                                        fminf(d1s[2][n], d1s[3][n]));
    }

    // d2: per s, min over the 4 waves of its subgroup; clamp; block sum
    float v = 0.0f;
    if (tid < SS) {
        const int sc = tid >> 5, sl = tid & 31;
        v = fminf(fminf(wmin[sc * 4 + 0][sl], wmin[sc * 4 + 1][sl]),
                  fminf(wmin[sc * 4 + 2][sl], wmin[sc * 4 + 3][sl]));
        if (v >= 1.0e30f) v = 0.0f;
    }
#pragma unroll
    for (int off = 32; off > 0; off >>= 1)
        v += __shfl_down(v, off, 64);
    if (tid < SS && lane == 0) red[wid] = v;   // wid 0,1
    __syncthreads();
    if (tid == 0) d2sum[bm] = red[0] + red[1];
}

// ---------------------------------------------------------------------------
// Kernel B: p2p sort + stick-breaking; last block finalizes everything.
// grid 128 x 256 threads; one thread per (b,n).
// ---------------------------------------------------------------------------
__global__ __launch_bounds__(256) void p2p_final_kernel(
    const float* __restrict__ d1,      // [256][2048]
    const float* __restrict__ probs,   // (B,M)
    const float* __restrict__ size_,   // (B,M,3)
    const float* __restrict__ d2sum,   // [256]
    float* __restrict__ partial,       // [128]
    unsigned int* __restrict__ counter,
    float* __restrict__ out)           // (4)
{
    const int tid = threadIdx.x;
    const int gid = blockIdx.x * 256 + tid;   // b*N + n
    const int b   = gid >> 11;
    const int n   = gid & (NN - 1);

    float d[16], p[16];
#pragma unroll
    for (int m = 0; m < 16; ++m)
        d[m] = d1[((size_t)(b * MM + m)) * NN + n];

    const float* pb = probs + b * MM;
#pragma unroll
    for (int k = 0; k < 16; ++k) p[k] = pb[k];

    // odd-even transposition sort, fully static register indices
#define CE(i, j)                                              \
    {                                                         \
        const bool c = d[i] > d[j];                           \
        const float td = c ? d[j] : d[i];                     \
        d[j] = c ? d[i] : d[j];  d[i] = td;                   \
        const float tp = c ? p[j] : p[i];                     \
        p[j] = c ? p[i] : p[j];  p[i] = tp;                   \
    }
#pragma unroll
    for (int r = 0; r < 16; ++r) {
        if ((r & 1) == 0) {
            CE(0, 1) CE(2, 3) CE(4, 5) CE(6, 7)
            CE(8, 9) CE(10, 11) CE(12, 13) CE(14, 15)
        } else {
            CE(1, 2) CE(3, 4) CE(5, 6) CE(7, 8)
            CE(9, 10) CE(11, 12) CE(13, 14)
        }
    }
#undef CE

    float acc = 1.0f, sum = 0.0f;
#pragma unroll
    for (int k = 0; k < 16; ++k) {
        sum += d[k] * p[k] * acc;
        acc *= (1.0f - p[k]);
    }

    const int wid  = tid >> 6;
    const int lane = tid & 63;
    __shared__ float red4[4];
#pragma unroll
    for (int off = 32; off > 0; off >>= 1)
        sum += __shfl_down(sum, off, 64);
    if (lane == 0) red4[wid] = sum;
    __syncthreads();

    __shared__ bool amLast;
    if (tid == 0) {
        const float bsum = red4[0] + red4[1] + red4[2] + red4[3];
        __hip_atomic_store(&partial[blockIdx.x], bsum,
                           __ATOMIC_RELEASE, __HIP_MEMORY_SCOPE_AGENT);
        const unsigned int prev = __hip_atomic_fetch_add(
            counter, 1u, __ATOMIC_ACQ_REL, __HIP_MEMORY_SCOPE_AGENT);
        amLast = (prev == 127u);
    }
    __syncthreads();
    if (!amLast) return;

    // ---- finalize (one block, 256 threads; tid == b*16 + m) ----
    const int fb = tid >> 4;

    __shared__ float  areaSh[256];
    __shared__ double redA[4];
    __shared__ double redB[4];

    const float s0 = size_[tid * 3 + 0];
    const float s1 = size_[tid * 3 + 1];
    const float s2 = size_[tid * 3 + 2];
    const float inner = powf(s0 * s1, 1.6f) * (1.0f / 3.0f)
                      + powf(s0 * s2, 1.6f) * (1.0f / 3.0f)
                      + powf(s1 * s2, 1.6f) * (1.0f / 3.0f);
    const float a = kFourPi * powf(inner, 0.625f);
    areaSh[tid] = a;
    __syncthreads();

    float asum = 0.0f;
#pragma unroll
    for (int mm = 0; mm < 16; ++mm) asum += areaSh[fb * 16 + mm];
    const float anorm = 16.0f * a / asum;   // M * area / sum_m area

    double t = (double)(d2sum[tid] * (1.0f / 128.0f)) * (double)probs[tid] * (double)anorm;
#pragma unroll
    for (int off = 32; off > 0; off >>= 1)
        t += __shfl_down(t, off, 64);
    if (lane == 0) redA[wid] = t;

    double u = 0.0;
    if (tid < 128) {
        const float pv = __hip_atomic_load(&partial[tid],
                                           __ATOMIC_ACQUIRE, __HIP_MEMORY_SCOPE_AGENT);
        u = (double)pv;
    }
#pragma unroll
    for (int off = 32; off > 0; off >>= 1)
        u += __shfl_down(u, off, 64);
    if (lane == 0) redB[wid] = u;

    __syncthreads();
    if (tid == 0) {
        const double prim_to_pcl = (redA[0] + redA[1] + redA[2] + redA[3]) / 256.0;    // /(B*M)
        const double pcl_to_prim = (redB[0] + redB[1] + redB[2] + redB[3]) / 32768.0;  // /(B*N)
        out[0] = (float)(pcl_to_prim + prim_to_pcl);
        out[1] = (float)pcl_to_prim;
        out[2] = (float)prim_to_pcl;
        out[3] = 0.0f;
    }
}

// ---------------------------------------------------------------------------

extern "C" void kernel_launch(void* const* d_in, const int* in_sizes, int n_in,
                              void* d_out, int out_size, void* d_ws, size_t ws_size,
                              hipStream_t stream) {
    const float* pcl   = (const float*)d_in[0];  // (B,N,M,3)
    const float* prim  = (const float*)d_in[1];  // (B,M,S,3)
    const float* size_ = (const float*)d_in[2];  // (B,M,3)
    const float* probs = (const float*)d_in[3];  // (B,M)
    float* out = (float*)d_out;

    float* d1            = (float*)d_ws;             // 256*2048 floats (2 MiB)
    float* d2sum         = d1 + (size_t)256 * NN;    // 256
    float* partial       = d2sum + 256;              // 128
    unsigned int* counter = (unsigned int*)(partial + 128);

    fused_dist_kernel<<<BB * MM, 1024, 0, stream>>>(pcl, prim, d1, d2sum, counter);
    p2p_final_kernel<<<128, 256, 0, stream>>>(d1, probs, size_, d2sum, partial, counter, out);
}